// Round 16
// baseline (93.132 us; speedup 1.0000x reference)
//
#include <hip/hip_runtime.h>
#include <math.h>

#define SEQLEN   2048
#define HIDDEN   1024
#define NMODES   32
#define CHANNELS 4096
#define NST      31      // carry slots (chunks 0..30)
#define CHB      16      // channels per block (states/out)
#define TPG      1024    // timesteps per chunk-group (16 chunks x 64)
#define NGC      2       // chunk groups

typedef float  f2    __attribute__((ext_vector_type(2)));
typedef short  s8v   __attribute__((ext_vector_type(8)));
typedef float  f32x4 __attribute__((ext_vector_type(4)));
union Frag { s8v s; unsigned u[4]; };

// ---- ws layout (bytes) ---------------------------------------------------
#define SZ_V  (1024*64*64*2)              // V table bf16, 8 MiB
#define SZ_M  (1024*64*64*2)              // M table bf16, 8 MiB
#define SZ_K  (1024*64*4)                 // kc f32, 256 KiB
#define OFF_M (SZ_V)
#define OFF_K (SZ_V + SZ_M)
#define OFF_S (SZ_V + SZ_M + SZ_K)        // states bf16 [ch][31][64]
#define SZ_S  (CHANNELS*NST*64*2)
#define OFF_U (OFF_S + SZ_S)              // staged u bf16, frag-ordered
#define SZ_U  ((CHANNELS/CHB)*NGC*CHB*1024*2)   // 16 MiB
#define WS_NEED ((size_t)OFF_U + SZ_U)

// ---- helpers -------------------------------------------------------------
__device__ __forceinline__ f2 pk_fma(f2 a, f2 b, f2 c) {
    f2 d; asm("v_pk_fma_f32 %0, %1, %2, %3" : "=v"(d) : "v"(a), "v"(b), "v"(c)); return d;
}
template <int CTRL>
__device__ __forceinline__ float dpp_add(float p) {
    int t = __builtin_amdgcn_update_dpp(0, __float_as_int(p), CTRL, 0xF, 0xF, true);
    return p + __int_as_float(t);
}
__device__ __forceinline__ float sum32_to16(float p) {
    p = dpp_add<0xB1>(p); p = dpp_add<0x4E>(p);
    p = dpp_add<0x124>(p); p = dpp_add<0x128>(p);
    p = dpp_add<0x142>(p);
    return p;
}
__device__ __forceinline__ unsigned cvt_pk_bf16(float lo, float hi) {
    unsigned d; asm("v_cvt_pk_bf16_f32 %0, %1, %2" : "=v"(d) : "v"(lo), "v"(hi)); return d;
}
__device__ __forceinline__ unsigned short bf16of(float x) {
    return (unsigned short)(cvt_pk_bf16(x, x) & 0xffffu);
}
__device__ __forceinline__ float bf2f(unsigned s) {
    return __uint_as_float(s << 16);
}

// one mode: A_disc (bilinear alpha=0.5) and B' = Cc .* B_disc (C folded)
__device__ __forceinline__ void coef1(
    const float* __restrict__ log_dt, const float* __restrict__ A_log,
    const float* __restrict__ A_imag, const float* __restrict__ Bp,
    const float* __restrict__ Cp, int h, int m,
    float& adr, float& adi, float& bpr, float& bpi)
{
    const int idx = h * NMODES + m;
    const float dt = expf(log_dt[h]);
    const float hd = 0.5f * dt;
    const float ar = -expf(A_log[idx]);
    const float ai = A_imag[idx];
    const float dr = 1.f - hd * ar, di = -hd * ai;
    const float inv = 1.f / (dr * dr + di * di);
    const float nr = 1.f + hd * ar, ni = hd * ai;
    adr = (nr * dr + ni * di) * inv;
    adi = (ni * dr - nr * di) * inv;
    const float tbr = dt * Bp[idx * 2], tbi = dt * Bp[idx * 2 + 1];
    const float bdr = (tbr * dr + tbi * di) * inv;
    const float bdi = (tbi * dr - tbr * di) * inv;
    const float cr = 2.f * Cp[idx * 2], ci = 2.f * Cp[idx * 2 + 1];
    bpr = cr * bdr - ci * bdi;
    bpi = cr * bdi + ci * bdr;
}

// A_disc for 8 modes of octet m0, packed into f2 pairs
__device__ __forceinline__ void octetA(
    const float* __restrict__ log_dt, const float* __restrict__ A_log,
    const float* __restrict__ A_imag, int h, int m0, f2 Ar[4], f2 Ai[4])
{
    float adr[8], adi[8];
    const float dt = expf(log_dt[h]);
    #pragma unroll
    for (int k = 0; k < 8; ++k) {
        const int idx = h * NMODES + m0 + k;
        const float hd = 0.5f * dt;
        const float ar = -expf(A_log[idx]), ai = A_imag[idx];
        const float dr = 1.f - hd * ar, di = -hd * ai;
        const float inv = 1.f / (dr * dr + di * di);
        const float nr = 1.f + hd * ar, ni = hd * ai;
        adr[k] = (nr * dr + ni * di) * inv;
        adi[k] = (ni * dr - nr * di) * inv;
    }
    #pragma unroll
    for (int p = 0; p < 4; ++p) { Ar[p] = f2{adr[2*p], adr[2*p+1]}; Ai[p] = f2{adi[2*p], adi[2*p+1]}; }
}

// ---- Kernel 0: per-h tables (parallel over h, mode, d) -------------------
__global__ __launch_bounds__(256) void ssm_tables(
    const float* __restrict__ log_dt, const float* __restrict__ Dp,
    const float* __restrict__ A_log, const float* __restrict__ A_imag,
    const float* __restrict__ Bp, const float* __restrict__ Cp,
    unsigned short* __restrict__ Vt, unsigned short* __restrict__ Mt,
    float* __restrict__ kct)
{
    const int h = blockIdx.x >> 3, dg = blockIdx.x & 7;
    const int tid = threadIdx.x, wv = tid >> 6, l = tid & 63;
    const int m = l & 31;
    const int d = (dg * 4 + wv) * 2 + (l >> 5);

    float adr, adi, bpr, bpi;
    coef1(log_dt, A_log, A_imag, Bp, Cp, h, m, adr, adi, bpr, bpi);

    float Pr = 1.f, Pi = 0.f, Qr = adr, Qi = adi;
    #pragma unroll
    for (int bit = 0; bit < 6; ++bit) {
        if ((d >> bit) & 1) { float t = Pr*Qr - Pi*Qi; Pi = Pr*Qi + Pi*Qr; Pr = t; }
        float tq = Qr*Qr - Qi*Qi; Qi = 2.f*Qr*Qi; Qr = tq;
    }
    const float wr  = Pr*bpr - Pi*bpi, wi  = Pr*bpi + Pi*bpr;   // A^d B'
    const float apr = Pr*adr - Pi*adi, api = Pr*adi + Pi*adr;   // A^{d+1}

    const size_t hb = (size_t)h * 64;
    Vt[(hb + m)      * 64 + (63 - d)] = bf16of(wr);
    Vt[(hb + 32 + m) * 64 + (63 - d)] = bf16of(wi);
    Mt[(hb + d) * 64 + m]       = bf16of(apr);
    Mt[(hb + d) * 64 + 32 + m]  = bf16of(-api);

    float s = sum32_to16(wr);
    if ((l & 31) == 16) kct[hb + d] = s + (d == 0 ? Dp[h] : 0.f);
}

// ---- shared staging: u tile (1024 t x 16 ch) -> frag-ordered bf16 LDS ----
__device__ __forceinline__ void stage_frag_u(
    const float* __restrict__ ug, unsigned short* __restrict__ ubuf, int tid)
{
    #pragma unroll
    for (int it = 0; it < 16; ++it) {
        const int t_l = it * 64 + (tid >> 2);
        const int c4  = (tid & 3) * 4;
        const float4 g = *(const float4*)(ug + (size_t)t_l * HIDDEN + c4);
        const int n = t_l >> 6, rr = t_l & 63, ksw = rr >> 5, r5 = rr & 31;
        const int lane = (r5 >> 3) * 16 + n, j = r5 & 7;
        const int base = (ksw * 64 + lane) * 8 + j;
        ubuf[(c4 + 0) * 1024 + base] = bf16of(g.x);
        ubuf[(c4 + 1) * 1024 + base] = bf16of(g.y);
        ubuf[(c4 + 2) * 1024 + base] = bf16of(g.z);
        ubuf[(c4 + 3) * 1024 + base] = bf16of(g.w);
    }
    __syncthreads();
}

// ---- Kernel 1: local chunk end states, Xend = V x U (MFMA, 16 cols) ------
template <int WS>
__global__ __launch_bounds__(256) void ssm_states(
    const float* __restrict__ input, const unsigned short* __restrict__ Vt,
    unsigned short* __restrict__ stb, unsigned short* __restrict__ ustg)
{
    __shared__ __align__(16) unsigned short ubuf[CHB * 1024];
    const int tid = threadIdx.x, wv = tid >> 6, l = tid & 63;
    const int chb = blockIdx.x >> 1, cg = blockIdx.x & 1;
    const int chbase = chb * CHB;
    const int b = chbase >> 10, h0 = chbase & (HIDDEN - 1);
    const int lr = l & 15, lk8 = ((l >> 4) & 3) * 8, lo = (l >> 4) * 4;

    stage_frag_u(input + ((size_t)b * SEQLEN + cg * TPG) * HIDDEN + h0, ubuf, tid);

    if (WS) {   // persist staged bf16 tile for ssm_out (stores overlap MFMA)
        uint4* ug4 = (uint4*)(ustg + (size_t)blockIdx.x * (CHB * 1024));
        const uint4* ub4 = (const uint4*)ubuf;
        #pragma unroll
        for (int it = 0; it < 8; ++it) {
            const int unit = it * 256 + tid;
            ug4[unit] = ub4[unit];
        }
    }

    #pragma unroll 1
    for (int c = 0; c < 4; ++c) {
        const int chl = wv * 4 + c, ch = chbase + chl, h = h0 + chl;
        Frag UB[2];
        UB[0].s = *(const s8v*)(ubuf + chl * 1024 + l * 8);
        UB[1].s = *(const s8v*)(ubuf + chl * 1024 + (64 + l) * 8);

        f32x4 acc[4];
        #pragma unroll
        for (int mt = 0; mt < 4; ++mt) { f32x4 z = {0.f,0.f,0.f,0.f}; acc[mt] = z; }

        const unsigned short* Vh = Vt + (size_t)h * 64 * 64;
        #pragma unroll
        for (int ks = 0; ks < 2; ++ks) {
            #pragma unroll
            for (int mt = 0; mt < 4; ++mt) {
                Frag VA; VA.s = *(const s8v*)(Vh + (16 * mt + lr) * 64 + ks * 32 + lk8);
                acc[mt] = __builtin_amdgcn_mfma_f32_16x16x32_bf16(
                    VA.s, UB[ks].s, acc[mt], 0, 0, 0);
            }
        }

        const int gslot = cg * 16 + lr;
        if (gslot < NST) {
            unsigned short* sp = stb + ((size_t)ch * NST + gslot) * 64;
            #pragma unroll
            for (int mt = 0; mt < 4; ++mt) {
                uint2 w;
                w.x = cvt_pk_bf16(acc[mt][0], acc[mt][1]);
                w.y = cvt_pk_bf16(acc[mt][2], acc[mt][3]);
                *(uint2*)(sp + 16 * mt + lo) = w;
            }
        }
    }
}

// ---- Kernel 2: PARALLEL prefix over chunk states (Hillis-Steele) ---------
// One block per channel; thread (slot, octet); 5 steps with Q <- Q^2.
__global__ __launch_bounds__(128) void ssm_combine_par(
    const float* __restrict__ log_dt, const float* __restrict__ A_log,
    const float* __restrict__ A_imag, unsigned short* __restrict__ stb)
{
    __shared__ float XR[32][4][8], XI[32][4][8];
    const int ch = blockIdx.x;
    const int t = threadIdx.x;
    const int slot = t & 31, oct = t >> 5;
    const int h = ch & (HIDDEN - 1), m0 = oct * 8;

    // P = A^64 for this octet
    f2 Qr[4], Qi[4];
    {
        f2 Ar[4], Ai[4];
        octetA(log_dt, A_log, A_imag, h, m0, Ar, Ai);
        #pragma unroll
        for (int p = 0; p < 4; ++p) { Qr[p] = Ar[p]; Qi[p] = Ai[p]; }
        #pragma unroll
        for (int s = 0; s < 6; ++s)
            #pragma unroll
            for (int p = 0; p < 4; ++p) {
                f2 nr = Qr[p]*Qr[p] - Qi[p]*Qi[p];
                f2 ni = Qr[p]*Qi[p]; ni = ni + ni;
                Qr[p] = nr; Qi[p] = ni;
            }
    }

    const bool act = slot < NST;
    unsigned short* sp = stb + ((size_t)ch * NST + slot) * 64;

    f2 Xr[4], Xi[4];
    if (act) {
        s8v vr_ = *(const s8v*)(sp + m0);
        s8v vi_ = *(const s8v*)(sp + 32 + m0);
        #pragma unroll
        for (int p = 0; p < 4; ++p) {
            Xr[p] = f2{bf2f((unsigned short)vr_[2*p]), bf2f((unsigned short)vr_[2*p+1])};
            Xi[p] = f2{bf2f((unsigned short)vi_[2*p]), bf2f((unsigned short)vi_[2*p+1])};
        }
    } else {
        #pragma unroll
        for (int p = 0; p < 4; ++p) { Xr[p] = f2{0.f,0.f}; Xi[p] = f2{0.f,0.f}; }
    }

    #pragma unroll
    for (int p = 0; p < 4; ++p) {
        XR[slot][oct][2*p] = Xr[p].x; XR[slot][oct][2*p+1] = Xr[p].y;
        XI[slot][oct][2*p] = Xi[p].x; XI[slot][oct][2*p+1] = Xi[p].y;
    }

    #pragma unroll
    for (int s = 1; s < 32; s <<= 1) {
        __syncthreads();
        f2 Yr[4], Yi[4];
        if (slot >= s) {
            #pragma unroll
            for (int p = 0; p < 4; ++p) {
                Yr[p] = f2{XR[slot-s][oct][2*p], XR[slot-s][oct][2*p+1]};
                Yi[p] = f2{XI[slot-s][oct][2*p], XI[slot-s][oct][2*p+1]};
            }
        }
        __syncthreads();
        if (slot >= s) {
            #pragma unroll
            for (int p = 0; p < 4; ++p) {
                Xr[p] = pk_fma(Qr[p], Yr[p], pk_fma(f2{-Qi[p].x,-Qi[p].y}, Yi[p], Xr[p]));
                Xi[p] = pk_fma(Qr[p], Yi[p], pk_fma(Qi[p], Yr[p], Xi[p]));
            }
            #pragma unroll
            for (int p = 0; p < 4; ++p) {
                XR[slot][oct][2*p] = Xr[p].x; XR[slot][oct][2*p+1] = Xr[p].y;
                XI[slot][oct][2*p] = Xi[p].x; XI[slot][oct][2*p+1] = Xi[p].y;
            }
        }
        // Q = Q^2
        #pragma unroll
        for (int p = 0; p < 4; ++p) {
            f2 nr = Qr[p]*Qr[p] - Qi[p]*Qi[p];
            f2 ni = Qr[p]*Qi[p]; ni = ni + ni;
            Qr[p] = nr; Qi[p] = ni;
        }
    }

    if (act) {
        uint4 wr, wi;
        wr.x = cvt_pk_bf16(Xr[0].x, Xr[0].y); wr.y = cvt_pk_bf16(Xr[1].x, Xr[1].y);
        wr.z = cvt_pk_bf16(Xr[2].x, Xr[2].y); wr.w = cvt_pk_bf16(Xr[3].x, Xr[3].y);
        wi.x = cvt_pk_bf16(Xi[0].x, Xi[0].y); wi.y = cvt_pk_bf16(Xi[1].x, Xi[1].y);
        wi.z = cvt_pk_bf16(Xi[2].x, Xi[2].y); wi.w = cvt_pk_bf16(Xi[3].x, Xi[3].y);
        *(uint4*)(sp + m0)      = wr;
        *(uint4*)(sp + 32 + m0) = wi;
    }
}

// ---- Kernel 3: Y = T x U + M x X (MFMA, 16 cols), two-half LDS flush -----
template <int WS>
__global__ __launch_bounds__(256) void ssm_out(
    const float* __restrict__ input, const unsigned short* __restrict__ ustg,
    const unsigned short* __restrict__ Mt, const float* __restrict__ kct,
    const unsigned short* __restrict__ stb, float* __restrict__ out)
{
    __shared__ __align__(16) unsigned short ubuf[CHB * 1024];  // u frags, then y tile
    __shared__ float kcP[CHB][128];   // reversed kc, zero-padded (d<0 -> 0)
    const int tid = threadIdx.x, wv = tid >> 6, l = tid & 63;
    const int chb = blockIdx.x >> 1, cg = blockIdx.x & 1;
    const int chbase = chb * CHB;
    const int b = chbase >> 10, h0 = chbase & (HIDDEN - 1);
    const int lr = l & 15, lk8 = ((l >> 4) & 3) * 8, lo = (l >> 4) * 4;

    #pragma unroll
    for (int q = 0; q < 8; ++q) {
        const int idx = q * 256 + tid, chl = idx >> 7, k = idx & 127;
        kcP[chl][k] = (k < 64) ? kct[(size_t)(h0 + chl) * 64 + (63 - k)] : 0.f;
    }
    if (WS) {   // staged u already frag-ordered in ws: straight coalesced copy
        const uint4* us4 = (const uint4*)(ustg + (size_t)blockIdx.x * (CHB * 1024));
        uint4* ub4 = (uint4*)ubuf;
        #pragma unroll
        for (int it = 0; it < 8; ++it) {
            const int unit = it * 256 + tid;
            ub4[unit] = us4[unit];
        }
        __syncthreads();
    } else {
        stage_frag_u(input + ((size_t)b * SEQLEN + cg * TPG) * HIDDEN + h0, ubuf, tid);
    }

    f32x4 acc[4][4];
    #pragma unroll
    for (int c = 0; c < 4; ++c) {
        const int chl = wv * 4 + c, ch = chbase + chl, h = h0 + chl;
        Frag UB[2];
        UB[0].s = *(const s8v*)(ubuf + chl * 1024 + l * 8);
        UB[1].s = *(const s8v*)(ubuf + chl * 1024 + (64 + l) * 8);

        #pragma unroll
        for (int mt = 0; mt < 4; ++mt) { f32x4 z = {0.f,0.f,0.f,0.f}; acc[c][mt] = z; }

        // XB (carry) loads issued FIRST so L2 latency hides under T-frag VALU
        const int gc = cg * 16 + lr;
        const bool xv = (gc > 0);
        Frag XB[2];
        #pragma unroll
        for (int ks = 0; ks < 2; ++ks) {
            if (xv) XB[ks].s = *(const s8v*)(stb + ((size_t)ch * NST + gc - 1) * 64 + ks * 32 + lk8);
            else { XB[ks].u[0] = XB[ks].u[1] = XB[ks].u[2] = XB[ks].u[3] = 0; }
        }

        // T x U
        #pragma unroll
        for (int ks = 0; ks < 2; ++ks) {
            #pragma unroll
            for (int mt = 0; mt < 4; ++mt) {
                const int base = 63 - 16 * mt + 32 * ks + lk8 - lr;
                float f[8];
                #pragma unroll
                for (int j = 0; j < 8; ++j) f[j] = kcP[chl][base + j];
                Frag TA;
                #pragma unroll
                for (int q = 0; q < 4; ++q) TA.u[q] = cvt_pk_bf16(f[2*q], f[2*q+1]);
                acc[c][mt] = __builtin_amdgcn_mfma_f32_16x16x32_bf16(
                    TA.s, UB[ks].s, acc[c][mt], 0, 0, 0);
            }
        }

        // M x X
        const unsigned short* Mh = Mt + (size_t)h * 64 * 64;
        #pragma unroll
        for (int ks = 0; ks < 2; ++ks) {
            #pragma unroll
            for (int mt = 0; mt < 4; ++mt) {
                Frag MA; MA.s = *(const s8v*)(Mh + (16 * mt + lr) * 64 + ks * 32 + lk8);
                acc[c][mt] = __builtin_amdgcn_mfma_f32_16x16x32_bf16(
                    MA.s, XB[ks].s, acc[c][mt], 0, 0, 0);
            }
        }
    }

    // two-half flush through the (verified) swizzled [512][32] y tile
    float* ob = out + ((size_t)b * SEQLEN + cg * TPG) * HIDDEN + h0;
    #pragma unroll
    for (int half = 0; half < 2; ++half) {
        __syncthreads();
        if ((lr >> 3) == half) {
            const int lr7 = lr & 7;
            #pragma unroll
            for (int c = 0; c < 4; ++c) {
                const int chl = wv * 4 + c;
                const int col = chl ^ (lr7 << 1);
                #pragma unroll
                for (int mt = 0; mt < 4; ++mt)
                    #pragma unroll
                    for (int r = 0; r < 4; ++r) {
                        const int t_loc = lr7 * 64 + 16 * mt + lo + r;
                        ubuf[t_loc * 32 + col] = bf16of(acc[c][mt][r]);
                    }
            }
        }
        __syncthreads();
        float* obh = ob + (size_t)half * 512 * HIDDEN;
        #pragma unroll
        for (int q = 0; q < 8; ++q) {
            const int idx = q * 256 + tid;
            const int t_loc = idx >> 2, a = idx & 3;
            const int lrt = (t_loc >> 6) & 7;
            const int blk = (a ^ (lrt >> 1)) * 4;
            const uint2 w = *(const uint2*)(ubuf + t_loc * 32 + blk);
            const float s0 = bf2f(w.x & 0xffffu), s1 = bf2f(w.x >> 16);
            const float s2 = bf2f(w.y & 0xffffu), s3 = bf2f(w.y >> 16);
            float4 o;
            if (lrt & 1) o = make_float4(s2, s3, s0, s1);
            else         o = make_float4(s0, s1, s2, s3);
            *(float4*)(obh + (size_t)t_loc * HIDDEN + a * 4) = o;
        }
    }
}

extern "C" void kernel_launch(void* const* d_in, const int* in_sizes, int n_in,
                              void* d_out, int out_size, void* d_ws, size_t ws_size,
                              hipStream_t stream) {
    const float* input  = (const float*)d_in[0];
    const float* log_dt = (const float*)d_in[1];
    const float* Dp     = (const float*)d_in[2];
    const float* A_log  = (const float*)d_in[3];
    const float* A_imag = (const float*)d_in[4];
    const float* Bp     = (const float*)d_in[5];
    const float* Cp     = (const float*)d_in[6];
    float* out = (float*)d_out;

    unsigned short* Vt  = (unsigned short*)d_ws;
    unsigned short* Mtb = (unsigned short*)((char*)d_ws + OFF_M);
    float*          kct = (float*)((char*)d_ws + OFF_K);
    unsigned short* stb = (unsigned short*)((char*)d_ws + OFF_S);
    unsigned short* ustg= (unsigned short*)((char*)d_ws + OFF_U);

    const bool ws_ok = (ws_size >= WS_NEED);

    ssm_tables<<<dim3(1024 * 8), dim3(256), 0, stream>>>(
        log_dt, Dp, A_log, A_imag, Bp, Cp, Vt, Mtb, kct);
    if (ws_ok)
        ssm_states<1><<<dim3((CHANNELS / CHB) * NGC), dim3(256), 0, stream>>>(
            input, Vt, stb, ustg);
    else
        ssm_states<0><<<dim3((CHANNELS / CHB) * NGC), dim3(256), 0, stream>>>(
            input, Vt, stb, ustg);
    ssm_combine_par<<<dim3(CHANNELS), dim3(128), 0, stream>>>(
        log_dt, A_log, A_imag, stb);
    if (ws_ok)
        ssm_out<1><<<dim3((CHANNELS / CHB) * NGC), dim3(256), 0, stream>>>(
            input, ustg, Mtb, kct, stb, out);
    else
        ssm_out<0><<<dim3((CHANNELS / CHB) * NGC), dim3(256), 0, stream>>>(
            input, ustg, Mtb, kct, stb, out);
}

// Round 18
// 84.296 us; speedup vs baseline: 1.1048x; 1.1048x over previous
//
#include <hip/hip_runtime.h>
#include <math.h>

#define SEQLEN   2048
#define HIDDEN   1024
#define NMODES   32
#define CHANNELS 4096
#define CHB      16      // channels per block
#define TPG      1024    // timesteps per chunk-group (16 chunks x 64)
#define XP       72      // xbuf inner stride (bf16), 144B rows: 16B-aligned

typedef float  f2    __attribute__((ext_vector_type(2)));
typedef short  s8v   __attribute__((ext_vector_type(8)));
typedef float  f32x4 __attribute__((ext_vector_type(4)));
union Frag { s8v s; unsigned u[4]; };

// ---- ws layout (bytes) ---------------------------------------------------
#define SZ_V  (1024*64*64*2)              // V table bf16, 8 MiB
#define SZ_M  (1024*64*64*2)              // M table bf16, 8 MiB
#define SZ_K  (1024*64*4)                 // kc f32, 256 KiB
#define OFF_M (SZ_V)
#define OFF_K (SZ_V + SZ_M)
#define OFF_C (OFF_K + SZ_K)              // carry f32 [ch][64], 1 MiB
#define SZ_C  (CHANNELS*64*4)
#define OFF_F (OFF_C + SZ_C)              // flags int[256]

// ---- helpers -------------------------------------------------------------
template <int CTRL>
__device__ __forceinline__ float dpp_add(float p) {
    int t = __builtin_amdgcn_update_dpp(0, __float_as_int(p), CTRL, 0xF, 0xF, true);
    return p + __int_as_float(t);
}
template <int CTRL>
__device__ __forceinline__ float dpp_shr(float x) {   // lane i <- lane i-s (0 fill)
    int t = __builtin_amdgcn_update_dpp(0, __float_as_int(x), CTRL, 0xF, 0xF, true);
    return __int_as_float(t);
}
__device__ __forceinline__ float sum32_to16(float p) {
    p = dpp_add<0xB1>(p); p = dpp_add<0x4E>(p);
    p = dpp_add<0x124>(p); p = dpp_add<0x128>(p);
    p = dpp_add<0x142>(p);
    return p;
}
__device__ __forceinline__ unsigned cvt_pk_bf16(float lo, float hi) {
    unsigned d; asm("v_cvt_pk_bf16_f32 %0, %1, %2" : "=v"(d) : "v"(lo), "v"(hi)); return d;
}
__device__ __forceinline__ unsigned short bf16of(float x) {
    return (unsigned short)(cvt_pk_bf16(x, x) & 0xffffu);
}
__device__ __forceinline__ float bf2f(unsigned s) {
    return __uint_as_float(s << 16);
}

__device__ __forceinline__ void mode_A(float dt, float al, float aim,
                                       float& adr, float& adi)
{
    const float hd = 0.5f * dt;
    const float ar = -expf(al);
    const float dr = 1.0f - hd * ar, di = -hd * aim;
    const float inv = 1.0f / (dr * dr + di * di);
    const float nr = 1.0f + hd * ar, ni = hd * aim;
    adr = (nr * dr + ni * di) * inv;
    adi = (ni * dr - nr * di) * inv;
}

__device__ __forceinline__ void coef1(
    const float* __restrict__ log_dt, const float* __restrict__ A_log,
    const float* __restrict__ A_imag, const float* __restrict__ Bp,
    const float* __restrict__ Cp, int h, int m,
    float& adr, float& adi, float& bpr, float& bpi)
{
    const int idx = h * NMODES + m;
    const float dt = expf(log_dt[h]);
    const float hd = 0.5f * dt;
    const float ar = -expf(A_log[idx]);
    const float ai = A_imag[idx];
    const float dr = 1.f - hd * ar, di = -hd * ai;
    const float inv = 1.f / (dr * dr + di * di);
    const float nr = 1.f + hd * ar, ni = hd * ai;
    adr = (nr * dr + ni * di) * inv;
    adi = (ni * dr - nr * di) * inv;
    const float tbr = dt * Bp[idx * 2], tbi = dt * Bp[idx * 2 + 1];
    const float bdr = (tbr * dr + tbi * di) * inv;
    const float bdi = (tbi * dr - tbr * di) * inv;
    const float cr = 2.f * Cp[idx * 2], ci = 2.f * Cp[idx * 2 + 1];
    bpr = cr * bdr - ci * bdi;
    bpi = cr * bdi + ci * bdr;
}

// ---- Kernel 0: per-h tables (parallel over h, mode, d) — R15 verbatim ----
__global__ __launch_bounds__(256) void ssm_tables(
    const float* __restrict__ log_dt, const float* __restrict__ Dp,
    const float* __restrict__ A_log, const float* __restrict__ A_imag,
    const float* __restrict__ Bp, const float* __restrict__ Cp,
    unsigned short* __restrict__ Vt, unsigned short* __restrict__ Mt,
    float* __restrict__ kct)
{
    const int h = blockIdx.x >> 3, dg = blockIdx.x & 7;
    const int tid = threadIdx.x, wv = tid >> 6, l = tid & 63;
    const int m = l & 31;
    const int d = (dg * 4 + wv) * 2 + (l >> 5);

    float adr, adi, bpr, bpi;
    coef1(log_dt, A_log, A_imag, Bp, Cp, h, m, adr, adi, bpr, bpi);

    float Pr = 1.f, Pi = 0.f, Qr = adr, Qi = adi;
    #pragma unroll
    for (int bit = 0; bit < 6; ++bit) {
        if ((d >> bit) & 1) { float t = Pr*Qr - Pi*Qi; Pi = Pr*Qi + Pi*Qr; Pr = t; }
        float tq = Qr*Qr - Qi*Qi; Qi = 2.f*Qr*Qi; Qr = tq;
    }
    const float wr  = Pr*bpr - Pi*bpi, wi  = Pr*bpi + Pi*bpr;   // A^d B'
    const float apr = Pr*adr - Pi*adi, api = Pr*adi + Pi*adr;   // A^{d+1}

    const size_t hb = (size_t)h * 64;
    Vt[(hb + m)      * 64 + (63 - d)] = bf16of(wr);
    Vt[(hb + 32 + m) * 64 + (63 - d)] = bf16of(wi);
    Mt[(hb + d) * 64 + m]       = bf16of(apr);
    Mt[(hb + d) * 64 + 32 + m]  = bf16of(-api);

    float s = sum32_to16(wr);
    if ((l & 31) == 16) kct[hb + d] = s + (d == 0 ? Dp[h] : 0.f);
}

// ---- staging: u tile (1024 t x 16 ch) -> frag-ordered bf16 LDS (R15) -----
__device__ __forceinline__ void stage_frag_u(
    const float* __restrict__ ug, unsigned short* __restrict__ ubuf, int tid)
{
    #pragma unroll
    for (int it = 0; it < 16; ++it) {
        const int t_l = it * 64 + (tid >> 2);
        const int c4  = (tid & 3) * 4;
        const float4 g = *(const float4*)(ug + (size_t)t_l * HIDDEN + c4);
        const int n = t_l >> 6, rr = t_l & 63, ksw = rr >> 5, r5 = rr & 31;
        const int lane = (r5 >> 3) * 16 + n, j = r5 & 7;
        const int base = (ksw * 64 + lane) * 8 + j;
        ubuf[(c4 + 0) * 1024 + base] = bf16of(g.x);
        ubuf[(c4 + 1) * 1024 + base] = bf16of(g.y);
        ubuf[(c4 + 2) * 1024 + base] = bf16of(g.z);
        ubuf[(c4 + 3) * 1024 + base] = bf16of(g.w);
    }
    __syncthreads();
}

// ---- Fused: states MFMA -> DPP prefix -> carry handoff -> out MFMA -------
// grid = 512: blockIdx 0..255 = cg0 (t 0..1023), 256..511 = cg1.
// LDS 78.3KB -> 2 blocks/CU -> all 512 co-resident (no deadlock).
__global__ __launch_bounds__(256) void ssm_fused(
    const float* __restrict__ input, const float* __restrict__ log_dt,
    const float* __restrict__ A_log, const float* __restrict__ A_imag,
    const unsigned short* __restrict__ Vt, const unsigned short* __restrict__ Mt,
    const float* __restrict__ kct, float* __restrict__ carry,
    int* __restrict__ flags, float* __restrict__ out)
{
    __shared__ __align__(16) unsigned short ubuf[CHB * 1024];   // u frags; later y tile
    __shared__ float kcP[CHB][128];
    __shared__ __align__(16) unsigned short xbuf[CHB][17][XP];  // abs states bf16, slot+1

    const int tid = threadIdx.x, wv = tid >> 6, l = tid & 63;
    const int cgp = blockIdx.x >> 8;           // 0 first (dispatch order)
    const int chb = blockIdx.x & 255;
    const int chbase = chb * CHB;
    const int b = chbase >> 10, h0 = chbase & (HIDDEN - 1);
    const int lr = l & 15, lk8 = ((l >> 4) & 3) * 8, lo = (l >> 4) * 4;

    // ---- stage kcP + u ----
    #pragma unroll
    for (int q = 0; q < 8; ++q) {
        const int idx = q * 256 + tid, chl = idx >> 7, k = idx & 127;
        kcP[chl][k] = (k < 64) ? kct[(size_t)(h0 + chl) * 64 + (63 - k)] : 0.f;
    }
    stage_frag_u(input + ((size_t)b * SEQLEN + cgp * TPG) * HIDDEN + h0, ubuf, tid);

    // ---- phase 1: V x U -> local chunk-end states (all 4 channels kept) ----
    f32x4 acc_s[4][4];
    #pragma unroll
    for (int c = 0; c < 4; ++c) {
        const int chl = wv * 4 + c, h = h0 + chl;
        Frag UB0, UB1;
        UB0.s = *(const s8v*)(ubuf + chl * 1024 + l * 8);
        UB1.s = *(const s8v*)(ubuf + chl * 1024 + (64 + l) * 8);
        #pragma unroll
        for (int mt = 0; mt < 4; ++mt) { f32x4 z = {0.f,0.f,0.f,0.f}; acc_s[c][mt] = z; }
        const unsigned short* Vh = Vt + (size_t)h * 64 * 64;
        #pragma unroll
        for (int mt = 0; mt < 4; ++mt) {
            Frag VA0, VA1;
            VA0.s = *(const s8v*)(Vh + (16 * mt + lr) * 64 + lk8);
            VA1.s = *(const s8v*)(Vh + (16 * mt + lr) * 64 + 32 + lk8);
            acc_s[c][mt] = __builtin_amdgcn_mfma_f32_16x16x32_bf16(VA0.s, UB0.s, acc_s[c][mt], 0, 0, 0);
            acc_s[c][mt] = __builtin_amdgcn_mfma_f32_16x16x32_bf16(VA1.s, UB1.s, acc_s[c][mt], 0, 0, 0);
        }
    }

    // ---- cg1: wait for cg0's carry (R7-proven agent-scope protocol) ----
    if (cgp == 1) {
        if (tid == 0)
            while (__hip_atomic_load(&flags[chb], __ATOMIC_ACQUIRE,
                                     __HIP_MEMORY_SCOPE_AGENT) == 0)
                __builtin_amdgcn_s_sleep(2);
        __syncthreads();
    }

    // ---- per-channel: Q64, carry injection, DPP prefix, xbuf/carry write ----
    // acc_s row map: mt0=Re mode lo+r, mt1=Re mode 16+lo+r, mt2=Im lo+r, mt3=Im 16+lo+r
    #pragma unroll
    for (int c = 0; c < 4; ++c) {
        const int chl = wv * 4 + c, ch = chbase + chl, h = h0 + chl;
        float QrA[4], QiA[4], QrB[4], QiB[4];
        {
            const float dt = expf(log_dt[h]);
            #pragma unroll
            for (int r = 0; r < 4; ++r) {
                mode_A(dt, A_log[h*NMODES + lo + r],      A_imag[h*NMODES + lo + r],      QrA[r], QiA[r]);
                mode_A(dt, A_log[h*NMODES + 16 + lo + r], A_imag[h*NMODES + 16 + lo + r], QrB[r], QiB[r]);
            }
            #pragma unroll
            for (int s = 0; s < 6; ++s)   // A -> A^64
                #pragma unroll
                for (int r = 0; r < 4; ++r) {
                    float tA = QrA[r]*QrA[r] - QiA[r]*QiA[r]; QiA[r] = 2.f*QrA[r]*QiA[r]; QrA[r] = tA;
                    float tB = QrB[r]*QrB[r] - QiB[r]*QiB[r]; QiB[r] = 2.f*QrB[r]*QiB[r]; QrB[r] = tB;
                }
        }

        float CrA[4] = {0,0,0,0}, CiA[4] = {0,0,0,0}, CrB[4] = {0,0,0,0}, CiB[4] = {0,0,0,0};
        if (cgp == 1 && lr == 0) {   // inject Q64*C into slot-0 local state
            const float* cb = carry + (size_t)ch * 64;
            #pragma unroll
            for (int r = 0; r < 4; ++r) {
                CrA[r] = cb[lo + r];      CrB[r] = cb[16 + lo + r];
                CiA[r] = cb[32 + lo + r]; CiB[r] = cb[48 + lo + r];
            }
            #pragma unroll
            for (int r = 0; r < 4; ++r) {
                acc_s[c][0][r] += QrA[r]*CrA[r] - QiA[r]*CiA[r];
                acc_s[c][2][r] += QrA[r]*CiA[r] + QiA[r]*CrA[r];
                acc_s[c][1][r] += QrB[r]*CrB[r] - QiB[r]*CiB[r];
                acc_s[c][3][r] += QrB[r]*CiB[r] + QiB[r]*CrB[r];
            }
        }

        // 4-step Hillis-Steele across the 16 slot-lanes (row_shr, zero-fill)
        #define PSTEP(CTRL) { \
            float Y0[4], Y1[4], Y2[4], Y3[4]; \
            _Pragma("unroll") for (int r = 0; r < 4; ++r) { \
                Y0[r] = dpp_shr<CTRL>(acc_s[c][0][r]); Y1[r] = dpp_shr<CTRL>(acc_s[c][1][r]); \
                Y2[r] = dpp_shr<CTRL>(acc_s[c][2][r]); Y3[r] = dpp_shr<CTRL>(acc_s[c][3][r]); } \
            _Pragma("unroll") for (int r = 0; r < 4; ++r) { \
                acc_s[c][0][r] += QrA[r]*Y0[r] - QiA[r]*Y2[r]; \
                acc_s[c][2][r] += QrA[r]*Y2[r] + QiA[r]*Y0[r]; \
                acc_s[c][1][r] += QrB[r]*Y1[r] - QiB[r]*Y3[r]; \
                acc_s[c][3][r] += QrB[r]*Y3[r] + QiB[r]*Y1[r]; } }
        #define QSQ { _Pragma("unroll") for (int r = 0; r < 4; ++r) { \
            float tA = QrA[r]*QrA[r] - QiA[r]*QiA[r]; QiA[r] = 2.f*QrA[r]*QiA[r]; QrA[r] = tA; \
            float tB = QrB[r]*QrB[r] - QiB[r]*QiB[r]; QiB[r] = 2.f*QrB[r]*QiB[r]; QrB[r] = tB; } }
        PSTEP(0x111) QSQ    // +1 slot, Q=A^64
        PSTEP(0x112) QSQ    // +2, A^128
        PSTEP(0x114) QSQ    // +4, A^256
        PSTEP(0x118)        // +8, A^512
        #undef PSTEP
        #undef QSQ

        // write absolute states -> xbuf slot lr+1 (bf16 B-frag rows)
        #pragma unroll
        for (int mt = 0; mt < 4; ++mt) {
            *(unsigned*)&xbuf[chl][lr + 1][16*mt + lo]     = cvt_pk_bf16(acc_s[c][mt][0], acc_s[c][mt][1]);
            *(unsigned*)&xbuf[chl][lr + 1][16*mt + lo + 2] = cvt_pk_bf16(acc_s[c][mt][2], acc_s[c][mt][3]);
        }
        // slot 0 = carry-in (cg1: C, cg0: zeros)
        if (lr == 0) {
            *(unsigned*)&xbuf[chl][0][lo]          = cvt_pk_bf16(CrA[0], CrA[1]);
            *(unsigned*)&xbuf[chl][0][lo + 2]      = cvt_pk_bf16(CrA[2], CrA[3]);
            *(unsigned*)&xbuf[chl][0][16 + lo]     = cvt_pk_bf16(CrB[0], CrB[1]);
            *(unsigned*)&xbuf[chl][0][16 + lo + 2] = cvt_pk_bf16(CrB[2], CrB[3]);
            *(unsigned*)&xbuf[chl][0][32 + lo]     = cvt_pk_bf16(CiA[0], CiA[1]);
            *(unsigned*)&xbuf[chl][0][32 + lo + 2] = cvt_pk_bf16(CiA[2], CiA[3]);
            *(unsigned*)&xbuf[chl][0][48 + lo]     = cvt_pk_bf16(CiB[0], CiB[1]);
            *(unsigned*)&xbuf[chl][0][48 + lo + 2] = cvt_pk_bf16(CiB[2], CiB[3]);
        }
        // cg0: publish chunk-15 absolute state (f32)
        if (cgp == 0 && lr == 15) {
            float* cb = carry + (size_t)ch * 64;
            #pragma unroll
            for (int r = 0; r < 4; ++r) {
                cb[lo + r]      = acc_s[c][0][r];
                cb[16 + lo + r] = acc_s[c][1][r];
                cb[32 + lo + r] = acc_s[c][2][r];
                cb[48 + lo + r] = acc_s[c][3][r];
            }
        }
    }

    if (cgp == 0) {
        __syncthreads();   // all waves' carry stores drained (vmcnt before barrier)
        if (tid == 0)
            __hip_atomic_store(&flags[chb], 1, __ATOMIC_RELEASE,
                               __HIP_MEMORY_SCOPE_AGENT);
    }
    __syncthreads();       // xbuf visible to all waves

    // ---- phase 3: Y = T x U + M x X (XB from xbuf) — R15-verified bodies ----
    f32x4 acc[4][4];
    #pragma unroll
    for (int c = 0; c < 4; ++c) {
        const int chl = wv * 4 + c, h = h0 + chl;
        Frag UB[2];
        UB[0].s = *(const s8v*)(ubuf + chl * 1024 + l * 8);
        UB[1].s = *(const s8v*)(ubuf + chl * 1024 + (64 + l) * 8);

        #pragma unroll
        for (int mt = 0; mt < 4; ++mt) { f32x4 z = {0.f,0.f,0.f,0.f}; acc[c][mt] = z; }

        Frag XB[2];
        XB[0].s = *(const s8v*)&xbuf[chl][lr][lk8];
        XB[1].s = *(const s8v*)&xbuf[chl][lr][32 + lk8];

        // T x U
        #pragma unroll
        for (int ks = 0; ks < 2; ++ks) {
            #pragma unroll
            for (int mt = 0; mt < 4; ++mt) {
                const int base = 63 - 16 * mt + 32 * ks + lk8 - lr;
                float f[8];
                #pragma unroll
                for (int j = 0; j < 8; ++j) f[j] = kcP[chl][base + j];
                Frag TA;
                #pragma unroll
                for (int q = 0; q < 4; ++q) TA.u[q] = cvt_pk_bf16(f[2*q], f[2*q+1]);
                acc[c][mt] = __builtin_amdgcn_mfma_f32_16x16x32_bf16(
                    TA.s, UB[ks].s, acc[c][mt], 0, 0, 0);
            }
        }
        // M x X
        const unsigned short* Mh = Mt + (size_t)h * 64 * 64;
        #pragma unroll
        for (int ks = 0; ks < 2; ++ks) {
            #pragma unroll
            for (int mt = 0; mt < 4; ++mt) {
                Frag MA; MA.s = *(const s8v*)(Mh + (16 * mt + lr) * 64 + ks * 32 + lk8);
                acc[c][mt] = __builtin_amdgcn_mfma_f32_16x16x32_bf16(
                    MA.s, XB[ks].s, acc[c][mt], 0, 0, 0);
            }
        }
    }

    // two-half flush through the swizzled [512][32] y tile (R15 verbatim)
    float* ob = out + ((size_t)b * SEQLEN + cgp * TPG) * HIDDEN + h0;
    #pragma unroll
    for (int half = 0; half < 2; ++half) {
        __syncthreads();
        if ((lr >> 3) == half) {
            const int lr7 = lr & 7;
            #pragma unroll
            for (int c = 0; c < 4; ++c) {
                const int chl = wv * 4 + c;
                const int col = chl ^ (lr7 << 1);
                #pragma unroll
                for (int mt = 0; mt < 4; ++mt)
                    #pragma unroll
                    for (int r = 0; r < 4; ++r) {
                        const int t_loc = lr7 * 64 + 16 * mt + ((l >> 4) * 4) + r;
                        ubuf[t_loc * 32 + col] = bf16of(acc[c][mt][r]);
                    }
            }
        }
        __syncthreads();
        float* obh = ob + (size_t)half * 512 * HIDDEN;
        #pragma unroll
        for (int q = 0; q < 8; ++q) {
            const int idx = q * 256 + tid;
            const int t_loc = idx >> 2, a = idx & 3;
            const int lrt = (t_loc >> 6) & 7;
            const int blk = (a ^ (lrt >> 1)) * 4;
            const uint2 w = *(const uint2*)(ubuf + t_loc * 32 + blk);
            const float s0 = bf2f(w.x & 0xffffu), s1 = bf2f(w.x >> 16);
            const float s2 = bf2f(w.y & 0xffffu), s3 = bf2f(w.y >> 16);
            float4 o;
            if (lrt & 1) o = make_float4(s2, s3, s0, s1);
            else         o = make_float4(s0, s1, s2, s3);
            *(float4*)(obh + (size_t)t_loc * HIDDEN + a * 4) = o;
        }
    }
}

extern "C" void kernel_launch(void* const* d_in, const int* in_sizes, int n_in,
                              void* d_out, int out_size, void* d_ws, size_t ws_size,
                              hipStream_t stream) {
    const float* input  = (const float*)d_in[0];
    const float* log_dt = (const float*)d_in[1];
    const float* Dp     = (const float*)d_in[2];
    const float* A_log  = (const float*)d_in[3];
    const float* A_imag = (const float*)d_in[4];
    const float* Bp     = (const float*)d_in[5];
    const float* Cp     = (const float*)d_in[6];
    float* out = (float*)d_out;

    unsigned short* Vt  = (unsigned short*)d_ws;
    unsigned short* Mtb = (unsigned short*)((char*)d_ws + OFF_M);
    float*          kct = (float*)((char*)d_ws + OFF_K);
    float*          carry = (float*)((char*)d_ws + OFF_C);
    int*            flags = (int*)((char*)d_ws + OFF_F);

    hipMemsetAsync(flags, 0, 256 * sizeof(int), stream);   // reset handoff flags
    ssm_tables<<<dim3(1024 * 8), dim3(256), 0, stream>>>(
        log_dt, Dp, A_log, A_imag, Bp, Cp, Vt, Mtb, kct);
    ssm_fused<<<dim3(512), dim3(256), 0, stream>>>(
        input, log_dt, A_log, A_imag, Vt, Mtb, kct, carry, flags, out);
}